// Round 6
// baseline (90.937 us; speedup 1.0000x reference)
//
#include <hip/hip_runtime.h>
#include <hip/hip_fp16.h>

constexpr int B    = 4;
constexpr int CIN  = 192;
constexpr int COUT = 192;
constexpr int NN   = 16384;
constexpr int KK   = 16;
constexpr int NG   = 4;    // groups
constexpr int GIN  = 48;   // fan_in per group
constexpr int GOUT = 48;   // out channels per group
constexpr int NT   = 64;   // nodes per block: 1024 blocks = 4/CU (proven geometry)
constexpr int TPB  = 192;
constexpr int IST  = 20;   // idx_lds row stride (pad 16->20, 16B-aligned)
constexpr int HST  = 52;   // h_lds row stride  (pad 48->52, 16B-aligned)

// ---------------------------------------------------------------------------
// Kernel 1: transpose + fp16 convert (unchanged from R5, ~7.5 us).
// ---------------------------------------------------------------------------
__global__ __launch_bounds__(256) void transpose_h(const float* __restrict__ x,
                                                   __half* __restrict__ xh) {
    __shared__ float tile[32][33];
    const int b  = blockIdx.z;
    const int n0 = blockIdx.x * 32;
    const int c0 = blockIdx.y * 32;
    const int tx = threadIdx.x;
    const int ty = threadIdx.y;
    const float* xb  = x  + (size_t)b * CIN * NN;
    __half*      xhb = xh + (size_t)b * NN * CIN;
#pragma unroll
    for (int i = 0; i < 32; i += 8)
        tile[ty + i][tx] = xb[(size_t)(c0 + ty + i) * NN + (n0 + tx)];
    __syncthreads();
#pragma unroll
    for (int i = 0; i < 32; i += 8) {
        const int c = c0 + tx, n = n0 + ty + i;
        xhb[((size_t)(c / GIN) * NN + n) * GIN + (c % GIN)] =
            __float2half(tile[tx][ty + i]);
    }
}

__device__ __forceinline__ void cvt8(uint4 u, float4& lo, float4& hi) {
    const __half2* h = (const __half2*)&u;
    const float2 f0 = __half22float2(h[0]), f1 = __half22float2(h[1]);
    const float2 f2 = __half22float2(h[2]), f3 = __half22float2(h[3]);
    lo = make_float4(f0.x, f0.y, f1.x, f1.y);
    hi = make_float4(f2.x, f2.y, f3.x, f3.y);
}
__device__ __forceinline__ void acc8(float4& lo, float4& hi, uint4 u) {
    float4 l, h; cvt8(u, l, h);
    lo.x += l.x; lo.y += l.y; lo.z += l.z; lo.w += l.w;
    hi.x += h.x; hi.y += h.y; hi.z += h.z; hi.w += h.w;
}
// one fp16 packed add level (v_pk_add_f16): exact inputs, single rounding
__device__ __forceinline__ uint4 pair8(uint4 a, uint4 b) {
    const __half2* ha = (const __half2*)&a;
    const __half2* hb = (const __half2*)&b;
    uint4 o;
    __half2* ho = (__half2*)&o;
    ho[0] = __hadd2(ha[0], hb[0]);
    ho[1] = __hadd2(ha[1], hb[1]);
    ho[2] = __hadd2(ha[2], hb[2]);
    ho[3] = __hadd2(ha[3], hb[3]);
    return o;
}

// issue all 17 loads for one node-row batch (statically unrolled)
__device__ __forceinline__ void issue17(const uint4* __restrict__ xg,
                                        const int* __restrict__ iprow,
                                        int gidx, int e, uint4 u[16], uint4& us) {
    const int4* ip = (const int4*)iprow;
    const int4 ja = ip[0], jb = ip[1], jc = ip[2], jd = ip[3];
    us    = xg[gidx];
    u[0]  = xg[ja.x * 6 + e];  u[1]  = xg[ja.y * 6 + e];
    u[2]  = xg[ja.z * 6 + e];  u[3]  = xg[ja.w * 6 + e];
    u[4]  = xg[jb.x * 6 + e];  u[5]  = xg[jb.y * 6 + e];
    u[6]  = xg[jb.z * 6 + e];  u[7]  = xg[jb.w * 6 + e];
    u[8]  = xg[jc.x * 6 + e];  u[9]  = xg[jc.y * 6 + e];
    u[10] = xg[jc.z * 6 + e];  u[11] = xg[jc.w * 6 + e];
    u[12] = xg[jd.x * 6 + e];  u[13] = xg[jd.y * 6 + e];
    u[14] = xg[jd.z * 6 + e];  u[15] = xg[jd.w * 6 + e];
}

// pair-sum (fp16) -> fp32 accumulate -> + (1+eps)*self -> write h row
__device__ __forceinline__ void consume17(const uint4 u[16], uint4 us, float e1,
                                          float* __restrict__ dst, int i, int e) {
    uint4 p0 = pair8(u[0],  u[1]),  p1 = pair8(u[2],  u[3]);
    uint4 p2 = pair8(u[4],  u[5]),  p3 = pair8(u[6],  u[7]);
    uint4 p4 = pair8(u[8],  u[9]),  p5 = pair8(u[10], u[11]);
    uint4 p6 = pair8(u[12], u[13]), p7 = pair8(u[14], u[15]);
    float4 aLo, aHi; cvt8(p0, aLo, aHi);
    acc8(aLo, aHi, p1); acc8(aLo, aHi, p2); acc8(aLo, aHi, p3);
    acc8(aLo, aHi, p4); acc8(aLo, aHi, p5); acc8(aLo, aHi, p6);
    acc8(aLo, aHi, p7);
    float4 sLo, sHi; cvt8(us, sLo, sHi);
    float4 lo, hi;
    lo.x = fmaf(e1, sLo.x, aLo.x); lo.y = fmaf(e1, sLo.y, aLo.y);
    lo.z = fmaf(e1, sLo.z, aLo.z); lo.w = fmaf(e1, sLo.w, aLo.w);
    hi.x = fmaf(e1, sHi.x, aHi.x); hi.y = fmaf(e1, sHi.y, aHi.y);
    hi.z = fmaf(e1, sHi.z, aHi.z); hi.w = fmaf(e1, sHi.w, aHi.w);
    float4* hp = (float4*)(dst + i * HST + e * 8);
    hp[0] = lo;
    hp[1] = hi;
}

// GEMM quarter: 4 output rows for this thread, direct 16B store
__device__ __forceinline__ void gemm4(const float* __restrict__ hbuf,
                                      const float4 wv[12], float bi,
                                      int q, int i4, float* __restrict__ orow) {
    float av[4];
#pragma unroll
    for (int t = 0; t < 4; ++t) {
        const float* hr = hbuf + (q * 16 + i4 * 4 + t) * HST;
        float s = bi;
#pragma unroll
        for (int ii = 0; ii < 12; ++ii) {
            const float4 hv = ((const float4*)hr)[ii];
            s = fmaf(wv[ii].x, hv.x, s);
            s = fmaf(wv[ii].y, hv.y, s);
            s = fmaf(wv[ii].z, hv.z, s);
            s = fmaf(wv[ii].w, hv.w, s);
        }
        av[t] = fmaxf(s, 0.0f);
    }
    ((float4*)orow)[i4] = make_float4(av[0], av[1], av[2], av[3]);
}

// ---------------------------------------------------------------------------
// Kernel 2: per-wave pipelined.  Per group g: [load wv(g)] [issue gather r0 of
// g+1] [GEMM half1 of g] [consume r0 -> h[nxt]] [issue r1] [GEMM half2]
// [consume r1] [barrier].  Double-buffered h_lds; ONE barrier per group.
// The 17-load batch is in flight across the GEMM half (sched_barrier fences
// pin the order; wv loaded BEFORE the batch so its vmcnt wait doesn't drain
// it).  Memory pipe (TA: 1 lane-addr/cy/CU, the measured wall) and VALU are
// both fed continuously -> GEMM's ~26 us hides under the 44 us gather.
// ---------------------------------------------------------------------------
__global__ __launch_bounds__(TPB, 3) void gin_fused(const __half* __restrict__ xh,
                                                    const int*   __restrict__ idx,
                                                    const float* __restrict__ w,
                                                    const float* __restrict__ bias,
                                                    const float* __restrict__ eps,
                                                    float* __restrict__ out) {
    __shared__ __align__(16) float h_lds[2][NT * HST];  // 26.6 KB
    __shared__ __align__(16) int   idx_lds[NT * IST];   // 5.1 KB

    const int tid = threadIdx.x;
    const int blk = blockIdx.x;
    const int b   = blk & 3;
    const int n0  = (blk >> 2) * NT;

    const float e1 = 1.0f + eps[0];

    {
        const int* gi = idx + ((size_t)b * NN + n0) * KK;
        for (int t = tid; t < NT * KK; t += TPB)
            idx_lds[(t >> 4) * IST + (t & 15)] = gi[t];
    }

    const int e    = tid % 6;    // 0..5  (uint4 slot in 96 B slice)
    const int isub = tid / 6;    // 0..31 (node sub-index)
    const int co   = tid % GOUT; // 0..47
    const int q    = tid / GOUT; // 0..3

    const __half* xb = xh + (size_t)b * NN * CIN;
    float*        ob = out + (size_t)b * COUT * NN;

    __syncthreads();

    // ---- prologue: gather group 0 into buf 0 ----
    {
        const uint4* xg = (const uint4*)xb;
#pragma unroll
        for (int r = 0; r < 2; ++r) {
            const int i = isub + 32 * r;
            uint4 u[16], us;
            issue17(xg, idx_lds + i * IST, (n0 + i) * 6 + e, e, u, us);
            consume17(u, us, e1, h_lds[0], i, e);
        }
    }
    __syncthreads();

#pragma unroll
    for (int g = 0; g < NG; ++g) {
        const int cur = g & 1, nxt = cur ^ 1;
        // weights/bias for THIS group first (vmcnt wait for these must not
        // drain the gather batch issued below)
        float4 wv[12];
        {
            const float* wr = w + (size_t)(g * GOUT + co) * GIN;
#pragma unroll
            for (int ii = 0; ii < 12; ++ii) wv[ii] = ((const float4*)wr)[ii];
        }
        const float bi = bias[g * GOUT + co];
        float* orow = ob + (size_t)(g * GOUT + co) * NN + n0 + q * 16;
        __builtin_amdgcn_sched_barrier(0);

        const uint4* xgn = (const uint4*)(xb + (size_t)(g + 1) * NN * GIN);

        uint4 u[16], us;
        if (g < NG - 1) {                       // issue r0 of group g+1
            issue17(xgn, idx_lds + isub * IST, (n0 + isub) * 6 + e, e, u, us);
        }
        __builtin_amdgcn_sched_barrier(0);
        gemm4(h_lds[cur], wv, bi, q, 0, orow);  // GEMM half 1 (loads in flight)
        gemm4(h_lds[cur], wv, bi, q, 1, orow);
        __builtin_amdgcn_sched_barrier(0);
        if (g < NG - 1) {                       // consume r0 -> h[nxt]
            consume17(u, us, e1, h_lds[nxt], isub, e);
        }
        __builtin_amdgcn_sched_barrier(0);
        uint4 v[16], vs;
        if (g < NG - 1) {                       // issue r1 of group g+1
            issue17(xgn, idx_lds + (isub + 32) * IST, (n0 + isub + 32) * 6 + e,
                    e, v, vs);
        }
        __builtin_amdgcn_sched_barrier(0);
        gemm4(h_lds[cur], wv, bi, q, 2, orow);  // GEMM half 2
        gemm4(h_lds[cur], wv, bi, q, 3, orow);
        __builtin_amdgcn_sched_barrier(0);
        if (g < NG - 1) {                       // consume r1 -> h[nxt]
            consume17(v, vs, e1, h_lds[nxt], isub + 32, e);
        }
        __syncthreads();   // h[nxt] complete; GEMM reads of h[cur] retired
    }
}

// ---------------------------------------------------------------------------
extern "C" void kernel_launch(void* const* d_in, const int* in_sizes, int n_in,
                              void* d_out, int out_size, void* d_ws, size_t ws_size,
                              hipStream_t stream) {
    const float* x      = (const float*)d_in[0];
    const int*   edge   = (const int*)  d_in[1];  // edge_index[0] = first half
    const float* weight = (const float*)d_in[2];
    const float* bias   = (const float*)d_in[3];
    const float* eps    = (const float*)d_in[4];
    float*       out    = (float*)d_out;
    __half*      xh     = (__half*)d_ws;          // B*N*192 halfs = 25.2 MB

    dim3 tblk(32, 8);
    dim3 tgrd(NN / 32, CIN / 32, B);
    transpose_h<<<tgrd, tblk, 0, stream>>>(x, xh);

    gin_fused<<<B * (NN / NT), TPB, 0, stream>>>(xh, edge, weight, bias, eps, out);
}